// Round 1
// baseline (281.559 us; speedup 1.0000x reference)
//
#include <hip/hip_runtime.h>

// ---------------------------------------------------------------------------
// HOI top-k, R=262144 x K=117, topk=100, thresh=0.05
//
// v2: row-gated scan. Since scores s = hoi * bs with bs = ps*os and
// hoi in [0,1), s <= bs. Therefore every candidate with s > CSEL=0.95
// lives in a row with bs > CSEL — ~0.13% of rows for this data (~340 rows).
//
//  Single fused kernel (last-block ticket pattern):
//   phase A (all blocks): stream ps/os (2 MB), append rows with bs > CSEL
//                         to a global row buffer (device-scope atomics).
//   phase B (last block): read ONLY the candidate rows of hoi (~156 KB),
//                         collect s > CSEL into LDS (~690 entries), bitonic
//                         sort (value desc, index asc = jax top_k tie order),
//                         write outputs.
//  Fallback (exact, distribution-independent): if row buffer overflowed, or
//  cnt < topk, or cnt > FCAP, phase B recomputes via 576-bin histogram over
//  the full matrix. Never taken on this data.
//
//  ASSUMPTION for the fast path: hoi <= 1.0 (true: jax.random.uniform [0,1)).
//  hoi > 1 inputs are only caught by the fallback when cnt < topk.
// ---------------------------------------------------------------------------

#define THRESH    0.05f
#define CSEL      0.95f        // fast-path collect threshold
#define NB        576          // slow-path histogram bins
#define BIN_BASE  15692        // (bits of 0.05f) >> 16
#define FCAP      2048         // sort capacity (power of 2), 16 KiB LDS
#define NEG_INF   __int_as_float(0xFF800000)

__device__ __forceinline__ int bin_of(float s) {
  // valid only for s > 0 (positive floats: bit order == value order)
  int b = (int)(__float_as_uint(s) >> 16) - BIN_BASE;
  return b > (NB - 1) ? (NB - 1) : b;
}

// ctrl layout (ints): [0]=row candidate count  [1]=blocks-done ticket

template <int KC>
__global__ __launch_bounds__(1024) void k_fused(
    const float* __restrict__ hoi, const float* __restrict__ ps,
    const float* __restrict__ os, const float4* __restrict__ pbox,
    const float4* __restrict__ obox, const int* __restrict__ ocls,
    int R, int Kc_rt, int* __restrict__ ctrl,
    float* __restrict__ row_v, int* __restrict__ row_i, int rowcap,
    float* __restrict__ out, int topk) {
  const int k = KC ? KC : Kc_rt;

  __shared__ float sv[FCAP];
  __shared__ int   si[FCAP];
  __shared__ int   wh[NB];          // slow path only
  __shared__ int   s_ticket, s_rows, s_T, s_cnt;

  // ---------------- phase A: row gate (all blocks, grid-stride) ----------
  for (int r = blockIdx.x * blockDim.x + threadIdx.x; r < R;
       r += gridDim.x * blockDim.x) {
    float bs = ps[r] * os[r];       // box_scores = p*o (matches ref assoc)
    if (bs > CSEL) {                // rare (~1.3e-3)
      int slot = atomicAdd(&ctrl[0], 1);
      if (slot < rowcap) { row_v[slot] = bs; row_i[slot] = r; }
    }
  }

  // ---------------- last-block handoff ----------------------------------
  __threadfence();                  // release: row_v/row_i visible device-wide
  __syncthreads();
  if (threadIdx.x == 0) s_ticket = atomicAdd(&ctrl[1], 1);
  __syncthreads();
  if (s_ticket != (int)gridDim.x - 1) return;   // not last finishing block
  __threadfence();                  // acquire: see all other blocks' writes

  // ---------------- phase B: collect + select (one block) ----------------
  if (threadIdx.x == 0) {
    s_rows = atomicAdd(&ctrl[0], 0);   // device-coherent read of final count
    s_cnt  = 0;
  }
  __syncthreads();
  const int rowcnt = s_rows;
  const bool rows_ok = (rowcnt <= rowcap);

  if (rows_ok) {
    const int tot = rowcnt * k;        // ~340*117 ~= 40K elements
    for (int t = threadIdx.x; t < tot; t += blockDim.x) {
      int c  = t / k;                  // KC=117 -> magic mul
      int kk = t - c * k;
      int r  = row_i[c];
      float s = hoi[r * k + kk] * row_v[c];
      if (s > CSEL) {
        int slot = atomicAdd(&s_cnt, 1);
        if (slot < FCAP) { sv[slot] = s; si[slot] = r * k + kk; }
      }
    }
  }
  __syncthreads();

  int cnt = s_cnt;
  bool ok = rows_ok && (cnt >= topk) && (cnt <= FCAP);

  if (!ok) {
    // slow-but-exact: full histogram + re-collect (correctness net)
    const int N = R * k;
    for (int b = threadIdx.x; b < NB; b += blockDim.x) wh[b] = 0;
    if (threadIdx.x == 0) s_cnt = 0;
    __syncthreads();
    for (int i = threadIdx.x; i < N; i += blockDim.x) {
      int q = i / k;
      float s = hoi[i] * (ps[q] * os[q]);
      if (s > THRESH) atomicAdd(&wh[bin_of(s)], 1);
    }
    __syncthreads();
    if (threadIdx.x == 0) {
      int cum = 0, T = 0;
      for (int b = NB - 1; b >= 0; --b) {
        cum += wh[b];
        if (cum >= topk) { T = b; break; }
      }
      s_T = T;
    }
    __syncthreads();
    const int T = s_T;
    for (int i = threadIdx.x; i < N; i += blockDim.x) {
      int q = i / k;
      float s = hoi[i] * (ps[q] * os[q]);
      if (s > THRESH && bin_of(s) >= T) {
        int slot = atomicAdd(&s_cnt, 1);
        if (slot < FCAP) { sv[slot] = s; si[slot] = i; }
      }
    }
    __syncthreads();
  }

  // ---------------- bitonic sort: value desc, index asc ------------------
  int m = s_cnt > FCAP ? FCAP : s_cnt;
  int P = 128;                 // >= topk; dynamic power-of-2 sort size
  while (P < m) P <<= 1;
  for (int t = m + threadIdx.x; t < P; t += blockDim.x) {
    sv[t] = NEG_INF;
    si[t] = 0x7FFFFFFF;
  }
  for (int kkk = 2; kkk <= P; kkk <<= 1) {
    for (int j = kkk >> 1; j > 0; j >>= 1) {
      __syncthreads();
      for (int i = threadIdx.x; i < P; i += blockDim.x) {
        int l = i ^ j;
        if (l > i) {
          float vi = sv[i], vl = sv[l];
          int ii = si[i], il = si[l];
          bool before = (vi > vl) || (vi == vl && ii < il);
          if (((i & kkk) == 0) != before) {
            sv[i] = vl; sv[l] = vi; si[i] = il; si[l] = ii;
          }
        }
      }
    }
  }
  __syncthreads();

  // ---------------- epilogue --------------------------------------------
  if ((int)threadIdx.x < topk) {
    int o = threadIdx.x;
    float v = sv[o];
    int idx = si[o];
    bool valid = (idx != 0x7FFFFFFF) && (v > THRESH);
    int safe = valid ? idx : 0;
    int pair = safe / k;
    int act = safe - pair * k;
    float4 pb = pbox[pair];
    float4 ob = obox[pair];
    // output: scores[100] | pboxes[400] | oboxes[400] | ocls[100] |
    //         action[100] | valid[100]   (all fp32)
    out[o] = valid ? v : 0.0f;
    float* pdst = out + topk + 4 * o;
    pdst[0] = pb.x; pdst[1] = pb.y; pdst[2] = pb.z; pdst[3] = pb.w;
    float* odst = out + 5 * topk + 4 * o;
    odst[0] = ob.x; odst[1] = ob.y; odst[2] = ob.z; odst[3] = ob.w;
    out[9 * topk + o] = (float)ocls[pair];
    out[10 * topk + o] = (float)act;
    out[11 * topk + o] = valid ? 1.0f : 0.0f;
  }
}

extern "C" void kernel_launch(void* const* d_in, const int* in_sizes, int n_in,
                              void* d_out, int out_size, void* d_ws, size_t ws_size,
                              hipStream_t stream) {
  const float* pbox = (const float*)d_in[0];
  const float* obox = (const float*)d_in[1];
  const float* ps   = (const float*)d_in[2];
  const float* os   = (const float*)d_in[3];
  const int*   ocls = (const int*)d_in[4];
  const float* hoi  = (const float*)d_in[5];
  float* out = (float*)d_out;

  const int R    = in_sizes[2];
  const int N    = in_sizes[5];
  const int Kc   = N / R;              // 117
  const int topk = out_size / 12;      // 100

  // ws: ctrl[64 ints] @0 | row_v @4096 | row_i after
  int* ctrl = (int*)d_ws;
  float* row_v = (float*)((char*)d_ws + 4096);
  size_t budget = (ws_size > 4096) ? (ws_size - 4096) / 8 : 512;
  int rowcap = budget > 4096 ? 4096 : (int)budget;
  int* row_i = (int*)((char*)d_ws + 4096 + (size_t)rowcap * sizeof(float));

  (void)hipMemsetAsync(d_ws, 0, 256, stream);   // zero ctrl

  int nb = (R + 1023) / 1024;          // 256 blocks for R=262144
  if (nb > 256) nb = 256;              // grid-stride covers larger R
  if (nb < 1) nb = 1;

  if (Kc == 117) {
    k_fused<117><<<nb, 1024, 0, stream>>>(hoi, ps, os, (const float4*)pbox,
        (const float4*)obox, ocls, R, Kc, ctrl, row_v, row_i, rowcap, out, topk);
  } else {
    k_fused<0><<<nb, 1024, 0, stream>>>(hoi, ps, os, (const float4*)pbox,
        (const float4*)obox, ocls, R, Kc, ctrl, row_v, row_i, rowcap, out, topk);
  }
}

// Round 2
// 199.806 us; speedup vs baseline: 1.4092x; 1.4092x over previous
//
#include <hip/hip_runtime.h>

// ---------------------------------------------------------------------------
// HOI top-k, R=262144 x K=117, topk=100, thresh=0.05
//
// v3: row-gated scan, TWO dispatches (no device fences — the stream boundary
// provides device-wide visibility; v2's per-wave __threadfence cost ~90 µs
// of serialized L2 maintenance).
//
//  K1 k_gate : wide kernel (1024 blocks x 256). Reads only ps/os (2 MB).
//              Since s = hoi*bs with hoi in [0,1), s <= bs; rows with
//              bs <= CSEL=0.95 cannot contain candidates. ~0.13% of rows
//              pass the gate; gated threads read their 117-float hoi row
//              (latency hidden by 4096 resident waves) and append s > CSEL
//              (~690 entries) to a global buffer.
//  K2 k_post : 1 block. If topk <= cnt <= FCAP: exact top-k is a subset of
//              the buffer -> bitonic sort (value desc, index asc = jax
//              top_k tie order), write outputs. Otherwise: exact
//              single-block recompute (576-bin histogram + collect) —
//              distribution-independent correctness net.
//
//  ASSUMPTION for the fast path: hoi <= 1.0 (true: jax.random.uniform).
//  hoi > 1 inputs are only caught by the fallback when cnt < topk.
// ---------------------------------------------------------------------------

#define THRESH    0.05f
#define CSEL      0.95f        // fast-path collect threshold
#define NB        576          // slow-path histogram bins
#define BIN_BASE  15692        // (bits of 0.05f) >> 16
#define FCAP      2048         // sort capacity (power of 2), 16 KiB LDS
#define NEG_INF   __int_as_float(0xFF800000)

__device__ __forceinline__ int bin_of(float s) {
  // valid only for s > 0 (positive floats: bit order == value order)
  int b = (int)(__float_as_uint(s) >> 16) - BIN_BASE;
  return b > (NB - 1) ? (NB - 1) : b;
}

// ctrl layout (ints): [0]=cand_cnt

template <int KC>
__global__ __launch_bounds__(256) void k_gate(
    const float* __restrict__ hoi, const float* __restrict__ ps,
    const float* __restrict__ os, int R, int Kc_rt,
    int* __restrict__ ctrl, float* __restrict__ cand_v,
    int* __restrict__ cand_i, int cap) {
  const int k = KC ? KC : Kc_rt;
  for (int r = blockIdx.x * blockDim.x + threadIdx.x; r < R;
       r += gridDim.x * blockDim.x) {
    float bs = ps[r] * os[r];       // box_scores = p*o (matches ref assoc)
    if (bs > CSEL) {                // rare (~1.3e-3 of rows)
      const float* row = hoi + (size_t)r * k;
      const int rbase = r * k;      // R*K = 30.7M < 2^31, int ok
#pragma unroll 4
      for (int kk = 0; kk < k; ++kk) {
        float s = row[kk] * bs;     // == hoi * (ps*os), bit-exact vs ref
        if (s > CSEL) {             // ~690 total across the grid
          int slot = atomicAdd(&ctrl[0], 1);
          if (slot < cap) { cand_v[slot] = s; cand_i[slot] = rbase + kk; }
        }
      }
    }
  }
}

__global__ __launch_bounds__(1024) void k_post(
    const float* __restrict__ hoi, const float* __restrict__ ps,
    const float* __restrict__ os, const float4* __restrict__ pbox,
    const float4* __restrict__ obox, const int* __restrict__ ocls,
    int N, int Kc, const int* __restrict__ ctrl,
    const float* __restrict__ cand_v, const int* __restrict__ cand_i,
    int cap, float* __restrict__ out, int topk) {
  __shared__ float sv[FCAP];
  __shared__ int si[FCAP];
  __shared__ int wh[NB];                   // slow path only
  __shared__ int s_T, s_cnt;

  int cnt = ctrl[0];
  bool fast = (cnt >= topk && cnt <= FCAP);

  if (fast) {
    for (int t = threadIdx.x; t < cnt; t += blockDim.x) {
      sv[t] = cand_v[t];
      si[t] = cand_i[t];
    }
    if (threadIdx.x == 0) s_cnt = cnt;
  } else {
    // slow-but-exact: full histogram + re-collect (correctness net)
    for (int b = threadIdx.x; b < NB; b += blockDim.x) wh[b] = 0;
    if (threadIdx.x == 0) s_cnt = 0;
    __syncthreads();
    for (int i = threadIdx.x; i < N; i += blockDim.x) {
      int q = i / Kc;
      float s = hoi[i] * (ps[q] * os[q]);
      if (s > THRESH) atomicAdd(&wh[bin_of(s)], 1);
    }
    __syncthreads();
    if (threadIdx.x == 0) {
      int cum = 0, T = 0;
      for (int b = NB - 1; b >= 0; --b) {
        cum += wh[b];
        if (cum >= topk) { T = b; break; }
      }
      s_T = T;
    }
    __syncthreads();
    const int T = s_T;
    for (int i = threadIdx.x; i < N; i += blockDim.x) {
      int q = i / Kc;
      float s = hoi[i] * (ps[q] * os[q]);
      if (s > THRESH && bin_of(s) >= T) {
        int slot = atomicAdd(&s_cnt, 1);
        if (slot < FCAP) { sv[slot] = s; si[slot] = i; }
      }
    }
  }
  __syncthreads();

  int m = s_cnt > FCAP ? FCAP : s_cnt;
  int P = 128;                 // >= topk; dynamic power-of-2 sort size
  while (P < m) P <<= 1;
  for (int t = m + threadIdx.x; t < P; t += blockDim.x) {
    sv[t] = NEG_INF;
    si[t] = 0x7FFFFFFF;
  }
  // bitonic sort [0,P): value desc, index asc (stable-top_k tie order)
  for (int kk = 2; kk <= P; kk <<= 1) {
    for (int j = kk >> 1; j > 0; j >>= 1) {
      __syncthreads();
      for (int i = threadIdx.x; i < P; i += blockDim.x) {
        int l = i ^ j;
        if (l > i) {
          float vi = sv[i], vl = sv[l];
          int ii = si[i], il = si[l];
          bool before = (vi > vl) || (vi == vl && ii < il);
          if (((i & kk) == 0) != before) {
            sv[i] = vl; sv[l] = vi; si[i] = il; si[l] = ii;
          }
        }
      }
    }
  }
  __syncthreads();

  if ((int)threadIdx.x < topk) {
    int o = threadIdx.x;
    float v = sv[o];
    int idx = si[o];
    bool valid = (idx != 0x7FFFFFFF) && (v > THRESH);
    int safe = valid ? idx : 0;
    int pair = safe / Kc;
    int act = safe - pair * Kc;
    float4 pb = pbox[pair];
    float4 ob = obox[pair];
    // output: scores[100] | pboxes[400] | oboxes[400] | ocls[100] |
    //         action[100] | valid[100]   (all fp32)
    out[o] = valid ? v : 0.0f;
    float* pdst = out + topk + 4 * o;
    pdst[0] = pb.x; pdst[1] = pb.y; pdst[2] = pb.z; pdst[3] = pb.w;
    float* odst = out + 5 * topk + 4 * o;
    odst[0] = ob.x; odst[1] = ob.y; odst[2] = ob.z; odst[3] = ob.w;
    out[9 * topk + o] = (float)ocls[pair];
    out[10 * topk + o] = (float)act;
    out[11 * topk + o] = valid ? 1.0f : 0.0f;
  }
}

extern "C" void kernel_launch(void* const* d_in, const int* in_sizes, int n_in,
                              void* d_out, int out_size, void* d_ws, size_t ws_size,
                              hipStream_t stream) {
  const float* pbox = (const float*)d_in[0];
  const float* obox = (const float*)d_in[1];
  const float* ps   = (const float*)d_in[2];
  const float* os   = (const float*)d_in[3];
  const int*   ocls = (const int*)d_in[4];
  const float* hoi  = (const float*)d_in[5];
  float* out = (float*)d_out;

  const int R    = in_sizes[2];
  const int N    = in_sizes[5];
  const int Kc   = N / R;              // 117
  const int topk = out_size / 12;      // 100

  // ws: ctrl[64 ints] @0 | cand_v @4096 | cand_i after
  int* ctrl = (int*)d_ws;
  float* cand_v = (float*)((char*)d_ws + 4096);
  size_t cand_budget = (ws_size > 4096) ? (ws_size - 4096) / 8 : 1024;
  int cap = cand_budget > 4096 ? 4096 : (int)cand_budget;
  int* cand_i = (int*)((char*)d_ws + 4096 + (size_t)cap * sizeof(float));

  (void)hipMemsetAsync(d_ws, 0, 256, stream);   // zero ctrl

  int nb = (R + 255) / 256;            // one row per thread
  if (nb > 1024) nb = 1024;            // grid-stride covers larger R
  if (nb < 1) nb = 1;

  if (Kc == 117) {
    k_gate<117><<<nb, 256, 0, stream>>>(hoi, ps, os, R, Kc, ctrl,
                                        cand_v, cand_i, cap);
  } else {
    k_gate<0><<<nb, 256, 0, stream>>>(hoi, ps, os, R, Kc, ctrl,
                                      cand_v, cand_i, cap);
  }
  k_post<<<1, 1024, 0, stream>>>(hoi, ps, os, (const float4*)pbox,
                                 (const float4*)obox, ocls, N, Kc, ctrl,
                                 cand_v, cand_i, cap, out, topk);
}